// Round 9
// baseline (972.468 us; speedup 1.0000x reference)
//
#include <hip/hip_runtime.h>
#include <math.h>

#define CD 512
#define CDCD (CD * CD)
#define QN 8000
#define UN 20000
#define BATCHN 128

typedef unsigned short u16;
typedef unsigned int u32;
typedef __attribute__((ext_vector_type(8))) __bf16 bf16x8;
typedef __attribute__((ext_vector_type(4))) float f32x4;

static __device__ __forceinline__ u16 f2bf(float x) {
    u32 u = __float_as_uint(x);
    return (u16)((u + 0x7fff + ((u >> 16) & 1)) >> 16);
}
static __device__ __forceinline__ float bf2f(u16 h) {
    return __uint_as_float(((u32)h) << 16);
}
static __device__ __forceinline__ u32 pck(u16 a, u16 b) {
    return (u32)a | ((u32)b << 16);
}

// ========= conv_a: fp32 rows -> split bf16 hi/lo, layout [64][n_pad][8] =========
// Optional rowlist: pack rows rowlist[0..n) into compact indices 0..n.
// n from device (*nrow) or nfix. Rows >= n zero-filled.
__global__ __launch_bounds__(256) void conv_a(
    const float* __restrict__ src, const int* __restrict__ rowlist,
    const int* __restrict__ nrow,
    u16* __restrict__ h, u16* __restrict__ l, int nfix)
{
    const int r = blockIdx.x * 256 + threadIdx.x;
    const int kc = blockIdx.y;
    const int n_pad = gridDim.x * 256;
    const int n = nrow ? *nrow : nfix;
    float4 v0 = make_float4(0.f, 0.f, 0.f, 0.f), v1 = v0;
    if (r < n) {
        const int row = rowlist ? rowlist[r] : r;
        v0 = *(const float4*)(src + (size_t)row * CD + kc * 8);
        v1 = *(const float4*)(src + (size_t)row * CD + kc * 8 + 4);
    }
    float a[8] = {v0.x, v0.y, v0.z, v0.w, v1.x, v1.y, v1.z, v1.w};
    u16 hh[8], ll[8];
#pragma unroll
    for (int e = 0; e < 8; e++) {
        hh[e] = f2bf(a[e]);
        ll[e] = f2bf(a[e] - bf2f(hh[e]));
    }
    size_t o = ((size_t)kc * n_pad + r) * 8;
    uint4 H = make_uint4(pck(hh[0],hh[1]), pck(hh[2],hh[3]), pck(hh[4],hh[5]), pck(hh[6],hh[7]));
    uint4 L = make_uint4(pck(ll[0],ll[1]), pck(ll[2],ll[3]), pck(ll[4],ll[5]), pck(ll[6],ll[7]));
    *(uint4*)(h + o) = H;
    *(uint4*)(l + o) = L;
}

// ========= conv_bw: 16 weight matrices W[512][512] -> Bp[k/8][col][k%8] hi/lo =========
#define NWC 16
struct WcJobs { const float* src[NWC]; u16* h[NWC]; u16* l[NWC]; };
// grid (2, 64, NWC)
__global__ __launch_bounds__(256) void conv_bw(WcJobs J)
{
    const int w = blockIdx.z;
    const float* src = J.src[w];
    const int col = blockIdx.x * 256 + threadIdx.x;
    const int kc = blockIdx.y;
    float a[8];
#pragma unroll
    for (int j = 0; j < 8; j++)
        a[j] = src[(size_t)(kc * 8 + j) * CD + col];
    u16 hh[8], ll[8];
#pragma unroll
    for (int e = 0; e < 8; e++) {
        hh[e] = f2bf(a[e]);
        ll[e] = f2bf(a[e] - bf2f(hh[e]));
    }
    size_t o = ((size_t)kc * CD + col) * 8;
    uint4 H = make_uint4(pck(hh[0],hh[1]), pck(hh[2],hh[3]), pck(hh[4],hh[5]), pck(hh[6],hh[7]));
    uint4 L = make_uint4(pck(ll[0],ll[1]), pck(ll[2],ll[3]), pck(ll[4],ll[5]), pck(ll[6],ll[7]));
    *(uint4*)(J.h[w] + o) = H;
    *(uint4*)(J.l[w] + o) = L;
}

// ========= MFMA split-bf16 GEMM (3-product fp32 emulation), 128x128 tile =========
// n from device (*nrow) or nfix; blocks with bm >= n exit early (uniform).
__global__ __launch_bounds__(256) void gemm_bf3(
    const u16* __restrict__ Ah, const u16* __restrict__ Al, int nfix,
    const int* __restrict__ nrow, int n_pad,
    const u16* __restrict__ Bh0, const u16* __restrict__ Bl0, float* __restrict__ C0,
    const u16* __restrict__ Bh1, const u16* __restrict__ Bl1, float* __restrict__ C1)
{
    const int n = nrow ? *nrow : nfix;
    const int bm = blockIdx.x * 128;
    if (bm >= n) return;
    __shared__ __align__(16) u16 As_h[4][128][8];
    __shared__ __align__(16) u16 As_l[4][128][8];
    __shared__ __align__(16) u16 Bs_h[4][128][8];
    __shared__ __align__(16) u16 Bs_l[4][128][8];
    const int which = blockIdx.y >> 2;
    const u16* Bh = which ? Bh1 : Bh0;
    const u16* Bl = which ? Bl1 : Bl0;
    float* C = which ? C1 : C0;
    const int bn = (blockIdx.y & 3) * 128;
    const int tid = threadIdx.x, lane = tid & 63, w = tid >> 6;
    const int wm = w >> 1, wn = w & 1;
    const int l15 = lane & 15, kq = lane >> 4;

    f32x4 acc[4][4];
#pragma unroll
    for (int i = 0; i < 4; i++)
#pragma unroll
        for (int j = 0; j < 4; j++) {
            acc[i][j][0] = 0.f; acc[i][j][1] = 0.f;
            acc[i][j][2] = 0.f; acc[i][j][3] = 0.f;
        }

    for (int kt = 0; kt < 16; ++kt) {
        if (kt) __syncthreads();
#pragma unroll
        for (int s = 0; s < 8; ++s) {
            int ci = tid + s * 256;
            int mat = ci >> 9, rem = ci & 511, kc = rem >> 7, pos = rem & 127;
            int kcg = kt * 4 + kc;
            const u16* g;
            u16* lds;
            if (mat == 0)      { g = Ah + ((size_t)kcg * n_pad + bm + pos) * 8; lds = &As_h[kc][pos][0]; }
            else if (mat == 1) { g = Al + ((size_t)kcg * n_pad + bm + pos) * 8; lds = &As_l[kc][pos][0]; }
            else if (mat == 2) { g = Bh + ((size_t)kcg * CD + bn + pos) * 8;    lds = &Bs_h[kc][pos][0]; }
            else               { g = Bl + ((size_t)kcg * CD + bn + pos) * 8;    lds = &Bs_l[kc][pos][0]; }
            *(uint4*)lds = *(const uint4*)g;
        }
        __syncthreads();
        bf16x8 ah[4], al[4], bh[4], bl[4];
#pragma unroll
        for (int f = 0; f < 4; ++f) {
            ah[f] = *(const bf16x8*)&As_h[kq][wm * 64 + f * 16 + l15][0];
            al[f] = *(const bf16x8*)&As_l[kq][wm * 64 + f * 16 + l15][0];
            bh[f] = *(const bf16x8*)&Bs_h[kq][wn * 64 + f * 16 + l15][0];
            bl[f] = *(const bf16x8*)&Bs_l[kq][wn * 64 + f * 16 + l15][0];
        }
#pragma unroll
        for (int i = 0; i < 4; ++i)
#pragma unroll
            for (int j = 0; j < 4; ++j) {
                acc[i][j] = __builtin_amdgcn_mfma_f32_16x16x32_bf16(ah[i], bh[j], acc[i][j], 0, 0, 0);
                acc[i][j] = __builtin_amdgcn_mfma_f32_16x16x32_bf16(ah[i], bl[j], acc[i][j], 0, 0, 0);
                acc[i][j] = __builtin_amdgcn_mfma_f32_16x16x32_bf16(al[i], bh[j], acc[i][j], 0, 0, 0);
            }
    }
#pragma unroll
    for (int i = 0; i < 4; ++i) {
        int rb = bm + wm * 64 + i * 16 + kq * 4;
#pragma unroll
        for (int j = 0; j < 4; ++j) {
            int col = bn + wn * 64 + j * 16 + l15;
#pragma unroll
            for (int r = 0; r < 4; ++r) {
                int row = rb + r;
                if (row < n) C[(size_t)row * CD + col] = acc[i][j][r];
            }
        }
    }
}

// ========== dot_rows: out[r] = H[sel?sel[r]:r] . v  (n from device or host) ==========
__global__ __launch_bounds__(256) void dot_rows(
    const float* __restrict__ H, const int* __restrict__ sel,
    const float* __restrict__ v, float* __restrict__ out, int nfix,
    const int* __restrict__ nrow)
{
    const int lane = threadIdx.x & 63;
    const int r = blockIdx.x * 4 + (threadIdx.x >> 6);
    const int n = nrow ? *nrow : nfix;
    if (r >= n) return;
    const int row = sel ? sel[r] : r;
    const float* h = H + (size_t)row * CD;
    float4 a0 = *(const float4*)(h + lane * 8);
    float4 a1 = *(const float4*)(h + lane * 8 + 4);
    float4 b0 = *(const float4*)(v + lane * 8);
    float4 b1 = *(const float4*)(v + lane * 8 + 4);
    float sv = a0.x * b0.x + a0.y * b0.y + a0.z * b0.z + a0.w * b0.w
             + a1.x * b1.x + a1.y * b1.y + a1.z * b1.z + a1.w * b1.w;
#pragma unroll
    for (int o = 32; o; o >>= 1) sv += __shfl_xor(sv, o, 64);
    if (lane == 0) out[r] = sv;
}

// === dot over device row list, scatter result to out[rowlist[r]] ===
__global__ __launch_bounds__(256) void dot_rows_gather(
    const float* __restrict__ H, const int* __restrict__ rowlist,
    const int* __restrict__ nrow,
    const float* __restrict__ v, float* __restrict__ out)
{
    const int lane = threadIdx.x & 63;
    const int r = blockIdx.x * 4 + (threadIdx.x >> 6);
    if (r >= *nrow) return;
    const int row = rowlist[r];
    const float* h = H + (size_t)row * CD;
    float4 a0 = *(const float4*)(h + lane * 8);
    float4 a1 = *(const float4*)(h + lane * 8 + 4);
    float4 b0 = *(const float4*)(v + lane * 8);
    float4 b1 = *(const float4*)(v + lane * 8 + 4);
    float sv = a0.x * b0.x + a0.y * b0.y + a0.z * b0.z + a0.w * b0.w
             + a1.x * b1.x + a1.y * b1.y + a1.z * b1.z + a1.w * b1.w;
#pragma unroll
    for (int o = 32; o; o >>= 1) sv += __shfl_xor(sv, o, 64);
    if (lane == 0) out[row] = sv;
}

// ========== wa_gemv6 ==========
__global__ __launch_bounds__(256) void wa_gemv6(
    const float* __restrict__ W6, const float* __restrict__ a6, float* __restrict__ wa)
{
    const int layer = blockIdx.y;
    const int lane = threadIdx.x & 63;
    const int r = blockIdx.x * 4 + (threadIdx.x >> 6);
    const float* Wr = W6 + (size_t)layer * CDCD + (size_t)r * CD;
    const float* ah = a6 + layer * 2 * CD + CD;
    float4 a0 = *(const float4*)(Wr + lane * 8);
    float4 a1 = *(const float4*)(Wr + lane * 8 + 4);
    float4 b0 = *(const float4*)(ah + lane * 8);
    float4 b1 = *(const float4*)(ah + lane * 8 + 4);
    float sv = a0.x * b0.x + a0.y * b0.y + a0.z * b0.z + a0.w * b0.w
             + a1.x * b1.x + a1.y * b1.y + a1.z * b1.z + a1.w * b1.w;
#pragma unroll
    for (int o = 32; o; o >>= 1) sv += __shfl_xor(sv, o, 64);
    if (lane == 0) wa[layer * CD + r] = sv;
}

// ================= parallel CSR build =================
struct Csr6 {
    const int* src[6]; const int* dst[6];
    int* cnt[6]; int* off[6]; int* cur[6]; int* srcs[6];
    int nd[6]; int base[6]; int ecum[7];
};

__global__ __launch_bounds__(256) void zero_ints(int* __restrict__ p, int n)
{
    for (int i = blockIdx.x * 256 + threadIdx.x; i < n; i += gridDim.x * 256)
        p[i] = 0;
}

__global__ __launch_bounds__(256) void csr_hist(Csr6 G)
{
    const int total = G.ecum[6];
    for (int idx = blockIdx.x * 256 + threadIdx.x; idx < total; idx += gridDim.x * 256) {
        int g = 0;
        while (idx >= G.ecum[g + 1]) g++;
        int e = idx - G.ecum[g];
        atomicAdd(&G.cnt[g][G.dst[g][e] - G.base[g]], 1);
    }
}

__global__ __launch_bounds__(1024) void csr_scan(Csr6 G)
{
    __shared__ int wsum[16];
    const int g = blockIdx.x;
    const int tid = threadIdx.x, lane = tid & 63, wid = tid >> 6;
    const int n = G.nd[g];
    int* cnt = G.cnt[g];
    int* off = G.off[g];
    int* cur = G.cur[g];

    int running = 0;
    for (int base = 0; base < n; base += 1024) {
        int idx = base + tid;
        int v0 = (idx < n) ? cnt[idx] : 0;
        int v = v0;
#pragma unroll
        for (int dlt = 1; dlt < 64; dlt <<= 1) {
            int t = __shfl_up(v, dlt, 64);
            if (lane >= dlt) v += t;
        }
        if (lane == 63) wsum[wid] = v;
        __syncthreads();
        if (wid == 0) {
            int wv = (lane < 16) ? wsum[lane] : 0;
#pragma unroll
            for (int dlt = 1; dlt < 16; dlt <<= 1) {
                int t = __shfl_up(wv, dlt, 64);
                if (lane >= dlt) wv += t;
            }
            if (lane < 16) wsum[lane] = wv;
        }
        __syncthreads();
        int wprefix = (wid > 0) ? wsum[wid - 1] : 0;
        int chunk_total = wsum[15];
        int excl = running + wprefix + (v - v0);
        if (idx < n) { off[idx] = excl; cur[idx] = excl; }
        running += chunk_total;
        __syncthreads();
    }
    if (tid == 0) off[n] = running;
}

__global__ __launch_bounds__(256) void csr_scatter(Csr6 G)
{
    const int total = G.ecum[6];
    for (int idx = blockIdx.x * 256 + threadIdx.x; idx < total; idx += gridDim.x * 256) {
        int g = 0;
        while (idx >= G.ecum[g + 1]) g++;
        int e = idx - G.ecum[g];
        int dl = G.dst[g][e] - G.base[g];
        int pos = atomicAdd(&G.cur[g][dl], 1);
        G.srcs[g][pos] = G.src[g][e];
    }
}

__global__ void mark_qsel(const int* __restrict__ qid, int* __restrict__ qsel)
{
    qsel[qid[threadIdx.x]] = 1;
}

// users of interest: user_id rows + usel flag; rank5[u] = compact index
__global__ void mark_user(const int* __restrict__ uid, int* __restrict__ usel,
                          int* __restrict__ umark, int* __restrict__ list,
                          int* __restrict__ nlist, int* __restrict__ rank5)
{
    int u = uid[threadIdx.x];
    usel[u] = 1;
    if (atomicExch(&umark[u], 1) == 0) {
        int p = atomicAdd(nlist, 1);
        list[p] = u;
        rank5[u] = p;
    }
}

// l5 sources: eu edges (src user-node, dst question) with dst in qsel
__global__ __launch_bounds__(256) void mark_l5(
    const int* __restrict__ esrc, const int* __restrict__ edst, int ne,
    const int* __restrict__ qsel, int* __restrict__ umark,
    int* __restrict__ list, int* __restrict__ nlist, int* __restrict__ rank5)
{
    for (int e = blockIdx.x * 256 + threadIdx.x; e < ne; e += gridDim.x * 256) {
        if (qsel[edst[e]]) {
            int u = esrc[e] - QN;
            if (atomicExch(&umark[u], 1) == 0) {
                int p = atomicAdd(nlist, 1);
                list[p] = u;
                rank5[u] = p;
            }
        }
    }
}

// f2-l4 sources: ue edges (src question, dst user-node) with dst user in usel
__global__ __launch_bounds__(256) void mark_l4(
    const int* __restrict__ esrc, const int* __restrict__ edst, int ne,
    const int* __restrict__ usel, int* __restrict__ qmark,
    int* __restrict__ qlist, int* __restrict__ nq, int* __restrict__ rank4)
{
    for (int e = blockIdx.x * 256 + threadIdx.x; e < ne; e += gridDim.x * 256) {
        if (usel[edst[e] - QN]) {
            int q = esrc[e];
            if (atomicExch(&qmark[q], 1) == 0) {
                int p = atomicAdd(nq, 1);
                qlist[p] = q;
                rank4[q] = p;
            }
        }
    }
}

// ================= GAT aggregate =================
// node = sel?sel[b]:b. src local idx = srcs[e]-src_base, then rank[] if given
// (compact z/s rows). dd index: dv_node? node : b. out: scatter_out? node : b.
__global__ __launch_bounds__(256) void gat_aggregate(
    const int* __restrict__ off, const int* __restrict__ srcs, int src_base,
    const int* __restrict__ rank,
    const int* __restrict__ sel, const int* __restrict__ nlimit,
    int scatter_out, int dv_node,
    const float* __restrict__ z, const float* __restrict__ s,
    const float* __restrict__ dvals,
    const float* __restrict__ base, float* __restrict__ out)
{
    const int b = blockIdx.x;
    if (nlimit && b >= *nlimit) return;
    const int node = sel ? sel[b] : b;
    const int orow = scatter_out ? node : b;
    const int tid = threadIdx.x;
    const int lane = tid & 63, wid = tid >> 6;
    const int beg = off[node], end = off[node + 1];

    float2 bacc = base ? *(const float2*)(base + (size_t)node * CD + tid * 2)
                       : make_float2(0.f, 0.f);
    if (beg == end) {
        *(float2*)(out + (size_t)orow * CD + tid * 2) = bacc;
        return;
    }
    const float dd = dvals[dv_node ? node : b];

    float m = -1e30f, den = 0.f;
    for (int e = beg + tid; e < end; e += 256) {
        int sr = srcs[e] - src_base;
        if (rank) sr = rank[sr];
        float sc = s[sr] + dd;
        sc = sc > 0.f ? sc : 0.01f * sc;
        if (sc > m) { den = den * __expf(m - sc) + 1.f; m = sc; }
        else den += __expf(sc - m);
    }
#pragma unroll
    for (int o = 32; o; o >>= 1) {
        float om = __shfl_xor(m, o, 64);
        float od = __shfl_xor(den, o, 64);
        float nm = fmaxf(m, om);
        den = den * __expf(m - nm) + od * __expf(om - nm);
        m = nm;
    }
    __shared__ float wm[4], wd[4];
    __shared__ float alpha_s[256];
    __shared__ int   src_s[256];
    if (lane == 0) { wm[wid] = m; wd[wid] = den; }
    __syncthreads();
    float M = fmaxf(fmaxf(wm[0], wm[1]), fmaxf(wm[2], wm[3]));
    float Dn = wd[0] * __expf(wm[0] - M) + wd[1] * __expf(wm[1] - M)
             + wd[2] * __expf(wm[2] - M) + wd[3] * __expf(wm[3] - M);
    float invD = 1.f / Dn;

    for (int c0 = beg; c0 < end; c0 += 256) {
        int e = c0 + tid;
        float al = 0.f; int sr = 0;
        if (e < end) {
            sr = srcs[e] - src_base;
            if (rank) sr = rank[sr];
            float sc = s[sr] + dd;
            sc = sc > 0.f ? sc : 0.01f * sc;
            al = __expf(sc - M) * invD;
        }
        __syncthreads();
        alpha_s[tid] = al; src_s[tid] = sr;
        __syncthreads();
        int cc = min(256, end - c0);
        for (int jj = 0; jj < cc; jj++) {
            const float* zr = z + (size_t)src_s[jj] * CD;
            float a = alpha_s[jj];
            float2 v = *(const float2*)(zr + tid * 2);
            bacc.x = fmaf(a, v.x, bacc.x);
            bacc.y = fmaf(a, v.y, bacc.y);
        }
    }
    *(float2*)(out + (size_t)orow * CD + tid * 2) = bacc;
}

// ================= attention fuse kn =================
__global__ __launch_bounds__(256) void fuse_kn(
    const float* __restrict__ kn, const float* __restrict__ kd,
    const float* __restrict__ ku, const float* __restrict__ Dm,
    const float* __restrict__ aw, const float* __restrict__ ab, float* __restrict__ out)
{
    const int i = blockIdx.x, tid = threadIdx.x;
    const int lane = tid & 63, wid = tid >> 6;
    const size_t ro = (size_t)i * CD + tid * 2;
    const int c = tid * 2;
    float2 vkn = *(const float2*)(kn + ro);
    float2 v1  = *(const float2*)(kd + ro);
    float2 v2  = *(const float2*)(ku + ro);
    float2 v3  = *(const float2*)(Dm + ro);
    float p1 = vkn.x*aw[c]      + vkn.y*aw[c+1]      + v1.x*aw[CD+c]      + v1.y*aw[CD+c+1];
    float p2 = vkn.x*aw[1024+c] + vkn.y*aw[1024+c+1] + v2.x*aw[1024+CD+c] + v2.y*aw[1024+CD+c+1];
    float p3 = vkn.x*aw[2048+c] + vkn.y*aw[2048+c+1] + v3.x*aw[2048+CD+c] + v3.y*aw[2048+CD+c+1];
#pragma unroll
    for (int o = 32; o; o >>= 1) {
        p1 += __shfl_xor(p1, o, 64); p2 += __shfl_xor(p2, o, 64); p3 += __shfl_xor(p3, o, 64);
    }
    __shared__ float r1[4], r2[4], r3[4];
    if (lane == 0) { r1[wid] = p1; r2[wid] = p2; r3[wid] = p3; }
    __syncthreads();
    float s1 = r1[0]+r1[1]+r1[2]+r1[3] + ab[0];
    float s2 = r2[0]+r2[1]+r2[2]+r2[3] + ab[1];
    float s3 = r3[0]+r3[1]+r3[2]+r3[3] + ab[2];
    float mm = fmaxf(s1, fmaxf(s2, s3));
    float e1 = __expf(s1-mm), e2 = __expf(s2-mm), e3 = __expf(s3-mm);
    float inv = 1.f / (e1 + e2 + e3);
    float w1 = e1*inv, w2 = e2*inv, w3 = e3*inv;
    float2 o_;
    o_.x = vkn.x + w1*v1.x + w2*v2.x + w3*v3.x;
    o_.y = vkn.y + w1*v1.y + w2*v2.y + w3*v3.y;
    *(float2*)(out + ro) = o_;
}

// ================= attention fuse ex =================
__global__ __launch_bounds__(256) void fuse_ex(
    const float* __restrict__ ex, const int* __restrict__ sel,
    const float* __restrict__ Bq, const float* __restrict__ Cq,
    const float* __restrict__ aw, const float* __restrict__ ab, float* __restrict__ out)
{
    const int i = blockIdx.x, tid = threadIdx.x;
    const int lane = tid & 63, wid = tid >> 6;
    const int exrow = sel ? sel[i] : i;
    const size_t eo = (size_t)exrow * CD + tid * 2;
    const size_t ro = (size_t)i * CD + tid * 2;
    const int c = tid * 2;
    float2 ve = *(const float2*)(ex + eo);
    float2 vb = *(const float2*)(Bq + ro);
    float2 vc = *(const float2*)(Cq + ro);
    const float* a3 = aw + 3 * 2 * CD;
    const float* a4 = aw + 4 * 2 * CD;
    float p1 = ve.x*a3[c] + ve.y*a3[c+1] + vb.x*a3[CD+c] + vb.y*a3[CD+c+1];
    float p2 = ve.x*a4[c] + ve.y*a4[c+1] + vc.x*a4[CD+c] + vc.y*a4[CD+c+1];
#pragma unroll
    for (int o = 32; o; o >>= 1) { p1 += __shfl_xor(p1, o, 64); p2 += __shfl_xor(p2, o, 64); }
    __shared__ float r1[4], r2[4];
    if (lane == 0) { r1[wid] = p1; r2[wid] = p2; }
    __syncthreads();
    float t1 = r1[0]+r1[1]+r1[2]+r1[3] + ab[3];
    float t2 = r2[0]+r2[1]+r2[2]+r2[3] + ab[4];
    float mm = fmaxf(t1, t2);
    float e1 = __expf(t1-mm), e2 = __expf(t2-mm);
    float inv = 1.f / (e1 + e2);
    float w1 = e1*inv, w2 = e2*inv;
    float2 o_;
    o_.x = ve.x + w1*vb.x + w2*vc.x;
    o_.y = ve.y + w1*vb.y + w2*vc.y;
    *(float2*)(out + ro) = o_;
}

// ===== final prediction (q_table-sparse) =====
__global__ __launch_bounds__(256) void final_pred(
    const float* __restrict__ sP, const float* __restrict__ kP,
    const float* __restrict__ dP, const float* __restrict__ kD,
    const float* __restrict__ W3, const float* __restrict__ b3,
    const float* __restrict__ q_table, const int* __restrict__ qid,
    float* __restrict__ out)
{
    const int b = blockIdx.x;
    const int tid = threadIdx.x, lane = tid & 63, wid = tid >> 6;
    __shared__ int   sidx[CD];
    __shared__ float sqv[CD];
    __shared__ int   snn;
    __shared__ float scnt[4], sacc[4];
    if (tid == 0) snn = 0;
    __syncthreads();
    const float* qrow = q_table + (size_t)qid[b] * CD;
    float cnt = 0.f;
    for (int i = tid; i < CD; i += 256) {
        float qv = qrow[i];
        if (qv != 0.f) {
            int p = atomicAdd(&snn, 1);
            sidx[p] = i; sqv[p] = qv;
            cnt += qv;
        }
    }
#pragma unroll
    for (int o = 32; o; o >>= 1) cnt += __shfl_xor(cnt, o, 64);
    if (lane == 0) scnt[wid] = cnt;
    __syncthreads();
    const int nn = snn;
    const float bb = b3[0];
    const float* sPr = sP + (size_t)b * CD;
    const float* dPr = dP + (size_t)b * CD;
    float acc = 0.f;
    for (int t = wid; t < nn; t += 4) {
        const int i = sidx[t];
        const float* kPr = kP + (size_t)i * CD;
        const float* kDr = kD + (size_t)i * CD;
        float o = 0.f;
#pragma unroll
        for (int p = 0; p < 8; p++) {
            int j = lane + (p << 6);
            float pv = sPr[j] + kPr[j];
            float dv = dPr[j] + kDr[j];
            float s1 = 1.f / (1.f + __expf(-pv));
            float s2 = 1.f / (1.f + __expf(-dv));
            o += (s1 - s2) * W3[j];
        }
#pragma unroll
        for (int ofs = 32; ofs; ofs >>= 1) o += __shfl_xor(o, ofs, 64);
        if (lane == 0) acc += sqv[t] / (1.f + __expf(-(o + bb)));
    }
    if (lane == 0) sacc[wid] = acc;
    __syncthreads();
    if (tid == 0)
        out[b] = (sacc[0] + sacc[1] + sacc[2] + sacc[3])
               / (scnt[0] + scnt[1] + scnt[2] + scnt[3]);
}

// ================= host orchestration =================
#define EXPAD 8192
#define STUPAD 20224
#define SMPAD 256

extern "C" void kernel_launch(void* const* d_in, const int* in_sizes, int n_in,
                              void* d_out, int out_size, void* d_ws, size_t ws_size,
                              hipStream_t stream)
{
    const int*   user_id      = (const int*)d_in[0];
    const int*   question_id  = (const int*)d_in[1];
    const float* q_table      = (const float*)d_in[2];
    const int*   e_dir        = (const int*)d_in[3];
    const int*   e_und        = (const int*)d_in[4];
    const int*   e_ke         = (const int*)d_in[5];
    const int*   e_ek         = (const int*)d_in[6];
    const int*   e_ue         = (const int*)d_in[7];
    const int*   e_eu         = (const int*)d_in[8];
    const float* user_emb     = (const float*)d_in[9];
    const float* question_emb = (const float*)d_in[10];
    const float* concept_emb  = (const float*)d_in[11];
    const float* gat_W        = (const float*)d_in[12];
    const float* gat_a        = (const float*)d_in[13];
    const float* attn_w       = (const float*)d_in[14];
    const float* attn_b       = (const float*)d_in[15];
    const float* W1           = (const float*)d_in[16];
    const float* W2           = (const float*)d_in[17];
    const float* W3           = (const float*)d_in[18];
    const float* b3           = (const float*)d_in[19];
    float* out = (float*)d_out;

    char* wptr = (char*)d_ws;
    auto alloc = [&](size_t bytes) -> void* {
        void* p = (void*)wptr;
        wptr += (bytes + 255) & ~(size_t)255;
        return p;
    };

    // zone: f1: z2 rows [0,8000), z4 rows [8000,16000), then z5 full [0,20000)
    //       f2: z2 [0,8000), z4c at +QN (compact), then z5c [0,nlist)
    float* zone = (float*)alloc((size_t)UN * CD * 4);
    float* z2 = zone;
    float* z4 = zone + (size_t)QN * CD;
    float* z5 = zone;
    float* z0 = (float*)alloc((size_t)CD * CD * 4);
    float* z1 = (float*)alloc((size_t)CD * CD * 4);
    float* z3 = (float*)alloc((size_t)CD * CD * 4);

    float* s0 = (float*)alloc((size_t)CD * 4);
    float* s1 = (float*)alloc((size_t)CD * 4);
    float* s2 = (float*)alloc((size_t)QN * 4);
    float* s3 = (float*)alloc((size_t)CD * 4);
    float* s4 = (float*)alloc((size_t)QN * 4);
    float* s5 = (float*)alloc((size_t)UN * 4);
    float* dv0 = (float*)alloc((size_t)CD * 4);
    float* dv1 = (float*)alloc((size_t)CD * 4);
    float* dv2 = (float*)alloc((size_t)CD * 4);
    float* dv3 = (float*)alloc((size_t)QN * 4);
    float* dv4 = (float*)alloc((size_t)UN * 4);
    float* dv5 = (float*)alloc((size_t)QN * 4);
    float* wa  = (float*)alloc((size_t)6 * CD * 4);

    float* kn1  = (float*)alloc((size_t)CD * CD * 4);
    float* ex1  = (float*)alloc((size_t)QN * CD * 4);
    float* stu1 = (float*)alloc((size_t)UN * CD * 4);
    float* kn2  = (float*)alloc((size_t)CD * CD * 4);
    float* kdir = (float*)alloc((size_t)CD * CD * 4);
    float* kund = (float*)alloc((size_t)CD * CD * 4);
    float* Dm   = (float*)alloc((size_t)CD * CD * 4);
    float* Bq   = (float*)alloc((size_t)QN * CD * 4);
    float* Cq   = (float*)alloc((size_t)QN * CD * 4);
    float* eb   = (float*)alloc((size_t)BATCHN * CD * 4);
    float* sb   = (float*)alloc((size_t)BATCHN * CD * 4);
    float* sP   = (float*)alloc((size_t)BATCHN * CD * 4);
    float* dP   = (float*)alloc((size_t)BATCHN * CD * 4);
    float* kP   = (float*)alloc((size_t)CD * CD * 4);
    float* kD   = (float*)alloc((size_t)CD * CD * 4);

    // split-bf16 A buffers
    u16* exH  = (u16*)alloc((size_t)64 * EXPAD * 8 * 2);
    u16* exL  = (u16*)alloc((size_t)64 * EXPAD * 8 * 2);
    u16* stuH = (u16*)alloc((size_t)64 * STUPAD * 8 * 2);
    u16* stuL = (u16*)alloc((size_t)64 * STUPAD * 8 * 2);
    u16* knH  = (u16*)alloc((size_t)64 * CD * 8 * 2);
    u16* knL  = (u16*)alloc((size_t)64 * CD * 8 * 2);
    u16* cH   = (u16*)alloc((size_t)64 * EXPAD * 8 * 2);   // f2-l4 compact / head small
    u16* cL   = (u16*)alloc((size_t)64 * EXPAD * 8 * 2);
    // 16 weight matrices: 0..11 = gat_W[f][l], 12..15 = W1lo, W1hi, W2lo, W2hi
    u16* BpH[NWC]; u16* BpL[NWC];
    for (int i = 0; i < NWC; i++) {
        BpH[i] = (u16*)alloc((size_t)64 * CD * 8 * 2);
        BpL[i] = (u16*)alloc((size_t)64 * CD * 8 * 2);
    }

    static const int g_ne[6]   = {4096, 8192, 40000, 40000, 100000, 100000};
    static const int g_nd[6]   = {512, 512, 512, QN, UN, QN};
    static const int g_base[6] = {0, 0, QN, 0, QN, 0};
    const int* g_edges[6] = {e_dir, e_und, e_ke, e_ek, e_ue, e_eu};

    // zeroed region: cnt6 | qsel | umark | nlist | usel | qmark | nq2
    int cnt_total = 0;
    for (int g = 0; g < 6; g++) cnt_total += g_nd[g];
    int* zbase = (int*)alloc((size_t)(cnt_total + QN + UN + 1 + UN + QN + 1) * 4);
    int* cnt6[6];
    {
        int o = 0;
        for (int g = 0; g < 6; g++) { cnt6[g] = zbase + o; o += g_nd[g]; }
    }
    int* qsel   = zbase + cnt_total;
    int* umark  = qsel + QN;
    int* nlist  = umark + UN;
    int* usel   = nlist + 1;
    int* qmark  = usel + UN;
    int* nq2    = qmark + QN;
    const int ZTOT = cnt_total + QN + UN + 1 + UN + QN + 1;

    int* cur6   = (int*)alloc((size_t)cnt_total * 4);
    int* list   = (int*)alloc((size_t)UN * 4);
    int* qlist2 = (int*)alloc((size_t)QN * 4);
    int* rank5  = (int*)alloc((size_t)UN * 4);
    int* rank4  = (int*)alloc((size_t)QN * 4);
    int* off[6]; int* srcs[6];
    for (int g = 0; g < 6; g++) {
        off[g]  = (int*)alloc((size_t)(g_nd[g] + 1) * 4);
        srcs[g] = (int*)alloc((size_t)g_ne[g] * 4);
    }

    Csr6 G;
    {
        int o = 0, ec = 0;
        for (int g = 0; g < 6; g++) {
            G.src[g] = g_edges[g];
            G.dst[g] = g_edges[g] + g_ne[g];
            G.cnt[g] = cnt6[g];
            G.off[g] = off[g];
            G.cur[g] = cur6 + o;
            G.srcs[g] = srcs[g];
            G.nd[g] = g_nd[g];
            G.base[g] = g_base[g];
            G.ecum[g] = ec;
            o += g_nd[g]; ec += g_ne[g];
        }
        G.ecum[6] = ec;
    }

    zero_ints<<<128, 256, 0, stream>>>(zbase, ZTOT);
    csr_hist<<<512, 256, 0, stream>>>(G);
    csr_scan<<<6, 1024, 0, stream>>>(G);
    csr_scatter<<<512, 256, 0, stream>>>(G);
    mark_qsel<<<1, BATCHN, 0, stream>>>(question_id, qsel);
    mark_user<<<1, BATCHN, 0, stream>>>(user_id, usel, umark, list, nlist, rank5);
    mark_l5<<<200, 256, 0, stream>>>(e_eu, e_eu + 100000, 100000, qsel, umark,
                                     list, nlist, rank5);
    mark_l4<<<200, 256, 0, stream>>>(e_ue, e_ue + 100000, 100000, usel, qmark,
                                     qlist2, nq2, rank4);

    // pre-convert all 16 weight matrices
    {
        WcJobs wj;
        for (int f = 0; f < 2; f++)
            for (int l = 0; l < 6; l++)
                wj.src[f * 6 + l] = gat_W + (size_t)(f * 6 + l) * CDCD;
        wj.src[12] = W1;
        wj.src[13] = W1 + (size_t)CDCD;
        wj.src[14] = W2;
        wj.src[15] = W2 + (size_t)CDCD;
        for (int i = 0; i < NWC; i++) { wj.h[i] = BpH[i]; wj.l[i] = BpL[i]; }
        conv_bw<<<dim3(2, 64, NWC), 256, 0, stream>>>(wj);
    }

    auto conv = [&](const float* src, const int* rl, const int* nr,
                    u16* h, u16* l, int nfix, int npad) {
        conv_a<<<dim3(npad / 256, 64), 256, 0, stream>>>(src, rl, nr, h, l, nfix);
    };
    auto bf3 = [&](const u16* Ah, const u16* Al, int nfix, const int* nr, int npad,
                   int b0, float* C0, int b1, float* C1) {
        dim3 g((nfix + 127) / 128, (b1 >= 0) ? 8 : 4);
        gemm_bf3<<<g, 256, 0, stream>>>(Ah, Al, nfix, nr, npad,
                                        BpH[b0], BpL[b0], C0,
                                        (b1 >= 0) ? BpH[b1] : nullptr,
                                        (b1 >= 0) ? BpL[b1] : nullptr, C1);
    };
    auto dots = [&](const float* H, const int* sel, const float* v, float* o,
                    int n, const int* nr) {
        dot_rows<<<(n + 3) / 4, 256, 0, stream>>>(H, sel, v, o, n, nr);
    };
    auto agg = [&](int g, int src_base, const int* rank, const int* sel,
                   const int* nlim, int sc, int dvn,
                   const float* z, const float* s, const float* dv,
                   const float* base, float* o, int nblk) {
        gat_aggregate<<<nblk, 256, 0, stream>>>(off[g], srcs[g], src_base, rank,
                                                sel, nlim, sc, dvn, z, s, dv, base, o);
    };

    auto run_fusion = [&](int f, const float* kn, const float* ex, const float* stu,
                          const int* selq, const int* selu,
                          float* kn_o, float* ex_o, float* stu_o) {
        const float* af  = gat_a  + (size_t)f * 6 * 2 * CD;
        const float* awf = attn_w + (size_t)f * 5 * 2 * CD;
        const float* abf = attn_b + (size_t)f * 5;
        const float* Wf  = gat_W  + (size_t)f * 6 * CDCD;
        const int bp = f * 6;

        conv(ex, nullptr, nullptr, exH, exL, QN, EXPAD);
        if (!selq) conv(stu, nullptr, nullptr, stuH, stuL, UN, STUPAD);
        conv(kn, nullptr, nullptr, knH, knL, CD, CD);

        wa_gemv6<<<dim3(128, 6), 256, 0, stream>>>(Wf, af, wa);

        // l0 + l1 (A = kn, MFMA dual)
        bf3(knH, knL, CD, nullptr, CD, bp + 0, z0, bp + 1, z1);
        dots(z0, nullptr, af + 0 * 2 * CD, s0, CD, nullptr);
        dots(z1, nullptr, af + 1 * 2 * CD, s1, CD, nullptr);
        dots(kn, nullptr, wa + 0 * CD, dv0, CD, nullptr);
        dots(kn, nullptr, wa + 1 * CD, dv1, CD, nullptr);
        agg(0, 0, nullptr, nullptr, nullptr, 0, 0, z0, s0, dv0, nullptr, kdir, CD);
        agg(1, 0, nullptr, nullptr, nullptr, 0, 0, z1, s1, dv1, nullptr, kund, CD);

        // l2 (A = ex; dual with l4 in fusion 1)
        if (!selq) {
            bf3(exH, exL, QN, nullptr, EXPAD, bp + 2, z2, bp + 4, z4);
        } else {
            bf3(exH, exL, QN, nullptr, EXPAD, bp + 2, z2, -1, nullptr);
        }
        dots(z2, nullptr, af + 2 * 2 * CD, s2, QN, nullptr);
        dots(kn, nullptr, wa + 2 * CD, dv2, CD, nullptr);
        agg(2, 0, nullptr, nullptr, nullptr, 0, 0, z2, s2, dv2, nullptr, Dm, CD);

        // l4
        if (!selq) {
            // fusion 1: z4 already computed (dual); stu1 only needed at `list` rows
            dots(z4, nullptr, af + 4 * 2 * CD, s4, QN, nullptr);
            dot_rows_gather<<<(UN + 3) / 4, 256, 0, stream>>>(stu, list, nlist,
                                                              wa + 4 * CD, dv4);
            agg(4, 0, nullptr, list, nlist, 1, 1, z4, s4, dv4, stu, stu_o, UN);
        } else {
            // fusion 2: compact-convert the ~640 live question rows, MFMA, rank-indexed
            conv(ex, qlist2, nq2, cH, cL, QN, EXPAD);
            bf3(cH, cL, QN, nq2, EXPAD, bp + 4, z4, -1, nullptr);
            dots(z4, nullptr, af + 4 * 2 * CD, s4, QN, nq2);
            dots(stu, selu, wa + 4 * CD, dv4, BATCHN, nullptr);
            agg(4, 0, rank4, selu, nullptr, 0, 0, z4, s4, dv4, stu, stu_o, BATCHN);
        }

        // l3 (A = kn)
        bf3(knH, knL, CD, nullptr, CD, bp + 3, z3, -1, nullptr);
        dots(z3, nullptr, af + 3 * 2 * CD, s3, CD, nullptr);
        if (!selq) {
            dots(ex, nullptr, wa + 3 * CD, dv3, QN, nullptr);
            agg(3, QN, nullptr, nullptr, nullptr, 0, 0, z3, s3, dv3, nullptr, Bq, QN);
        } else {
            dots(ex, selq, wa + 3 * CD, dv3, BATCHN, nullptr);
            agg(3, QN, nullptr, selq, nullptr, 0, 0, z3, s3, dv3, nullptr, Bq, BATCHN);
        }

        // l5 (A = stu) — writes zone; all zone consumers above have run
        if (!selq) {
            bf3(stuH, stuL, UN, nullptr, STUPAD, bp + 5, z5, -1, nullptr);
            dots(z5, nullptr, af + 5 * 2 * CD, s5, UN, nullptr);
            dots(ex, nullptr, wa + 5 * CD, dv5, QN, nullptr);
            agg(5, QN, nullptr, nullptr, nullptr, 0, 0, z5, s5, dv5, nullptr, Cq, QN);
        } else {
            conv(stu, list, nlist, stuH, stuL, UN, STUPAD);
            bf3(stuH, stuL, UN, nlist, STUPAD, bp + 5, z5, -1, nullptr);
            dots(z5, nullptr, af + 5 * 2 * CD, s5, UN, nlist);
            dots(ex, selq, wa + 5 * CD, dv5, BATCHN, nullptr);
            agg(5, QN, rank5, selq, nullptr, 0, 0, z5, s5, dv5, nullptr, Cq, BATCHN);
        }

        fuse_kn<<<CD, 256, 0, stream>>>(kn, kdir, kund, Dm, awf, abf, kn_o);
        fuse_ex<<<selq ? BATCHN : QN, 256, 0, stream>>>(ex, selq, Bq, Cq, awf, abf, ex_o);
    };

    run_fusion(0, concept_emb, question_emb, user_emb, nullptr, nullptr,
               kn1, ex1, stu1);
    run_fusion(1, kn1, ex1, stu1, question_id, user_id,
               kn2, eb, sb);

    // prediction head (all MFMA)
    conv(sb, nullptr, nullptr, cH, cL, BATCHN, SMPAD);
    bf3(cH, cL, BATCHN, nullptr, SMPAD, 12, sP, -1, nullptr);
    conv(eb, nullptr, nullptr, cH, cL, BATCHN, SMPAD);
    bf3(cH, cL, BATCHN, nullptr, SMPAD, 14, dP, -1, nullptr);
    conv(kn2, nullptr, nullptr, knH, knL, CD, CD);
    bf3(knH, knL, CD, nullptr, CD, 13, kP, 15, kD);
    final_pred<<<BATCHN, 256, 0, stream>>>(sP, kP, dP, kD, W3, b3, q_table, question_id, out);
}